// Round 10
// baseline (570.651 us; speedup 1.0000x reference)
//
#include <hip/hip_runtime.h>
#include <math.h>

#define Bb 256
#define Ss 512
#define Tt 20
#define Ee 25
#define Hh 128
#define SKIPn 64
#define H4n 512
#define BSn (Bb*Ss)
#define MG 4             // batch rows per scan block (replicated 4x in M)
#define HP 160           // h16 LDS row pitch in halves: 80 words == 16 mod 32 -> free 2-way
#define LOG2E 1.4426950408889634f
#define WFRAG_SZ 4096    // halves per (kt,g) fragment plane: 128 cols x 32 k

typedef _Float16 f16x8 __attribute__((ext_vector_type(8)));
typedef float f32x4 __attribute__((ext_vector_type(4)));

__device__ __forceinline__ float rcpf(float x) { return __builtin_amdgcn_rcpf(x); }
__device__ __forceinline__ float exp2f_(float x) { return __builtin_amdgcn_exp2f(x); }

// Barrier that waits only on LDS ops (lgkmcnt(0)); leaves vmcnt in flight.
__device__ __forceinline__ void lgkm_barrier() {
    __asm__ __volatile__("" ::: "memory");
    __builtin_amdgcn_s_waitcnt(0xC07F);
    __builtin_amdgcn_s_barrier();
    __asm__ __volatile__("" ::: "memory");
}

// ---------------- Kernel 0: weight pre-fragmentation (coalesced fragment layout) ----------------
// Blocks 0..55: wfrag[dir][kt][g][col][kk] = gs[g]*W[32kt+kk][g*128+col] (fp16)
// Blocks 56..63: wkfrag[kt][j][kk] = Wk[32kt+kk][j] (fp16)
__global__ void __launch_bounds__(128)
frag_kernel(const float* __restrict__ Kf, const float* __restrict__ Rf,
            const float* __restrict__ Skf,
            const float* __restrict__ Kb, const float* __restrict__ Rb,
            const float* __restrict__ Skb,
            const float* __restrict__ Wk,
            _Float16* __restrict__ wfrag, _Float16* __restrict__ wkfrag)
{
    const int col = threadIdx.x;
    if (blockIdx.x < 56) {
        const int dir = blockIdx.x / 28;
        const int rem = blockIdx.x % 28;
        const int kt = rem >> 2, g = rem & 3;
        const float* Kw = dir ? Kb : Kf;
        const float* Rw = dir ? Rb : Rf;
        const float* Sw = dir ? Skb : Skf;
        const float gsv = (g == 2) ? 2.0f * LOG2E : LOG2E;
        const int n = g * Hh + col;
        _Float16* dst = wfrag + ((size_t)(dir * 28 + rem)) * WFRAG_SZ + col * 32;
#pragma unroll
        for (int kk = 0; kk < 32; kk++) {
            const int k = 32 * kt + kk;
            float x;
            if (k < 32)        x = (k < Ee) ? Kw[k * H4n + n] : 0.0f;
            else if (k < 160)  x = Rw[(k - 32) * H4n + n];
            else               x = Sw[(k - 160) * H4n + n];
            dst[kk] = (_Float16)(x * gsv);
        }
    } else {
        const int kt = blockIdx.x - 56;
        _Float16* dst = wkfrag + (size_t)kt * WFRAG_SZ + col * 32;
#pragma unroll
        for (int kk = 0; kk < 32; kk++)
            dst[kk] = (_Float16)Wk[(32 * kt + kk) * Hh + col];
    }
}

// ---------------- Kernel 1: fused pool (+masks) and skips cvt ----------------
__global__ void __launch_bounds__(256)
poolcvt_kernel(const int* __restrict__ tags, const float* __restrict__ table,
               const float* __restrict__ skips,
               _Float16* __restrict__ gru16, float* __restrict__ maskf,
               float* __restrict__ maskt, _Float16* __restrict__ skips16)
{
    if (blockIdx.x >= BSn / 8) {
        // cvt part: flat fp32->fp16, 2048 elems/block
        const size_t i = ((size_t)(blockIdx.x - BSn / 8) * 256 + threadIdx.x) * 8;
        f32x4 a = *(const f32x4*)(skips + i);
        f32x4 b = *(const f32x4*)(skips + i + 4);
        f16x8 o;
#pragma unroll
        for (int j = 0; j < 4; j++) { o[j] = (_Float16)a[j]; o[j + 4] = (_Float16)b[j]; }
        *(f16x8*)(skips16 + i) = o;
        return;
    }
    int group = blockIdx.x * 8 + (threadIdx.x >> 5);
    int lane = threadIdx.x & 31;
    int b = group >> 9;          // group = b*Ss + t
    int t = group & (Ss - 1);
    const int* tg = tags + (size_t)group * Tt;
    const int el = (lane < Ee) ? lane : (Ee - 1);   // lanes 25..31 read a valid dup

    int tagv[Tt];
#pragma unroll
    for (int tt = 0; tt < Tt; tt++) tagv[tt] = tg[tt];

    float vv[Tt];
#pragma unroll
    for (int tt = 0; tt < Tt; tt++)
        vv[tt] = table[(size_t)tagv[tt] * Ee + el];   // independent, unconditional

    float acc = 0.0f;
    int cnt = 0;
#pragma unroll
    for (int tt = 0; tt < Tt; tt++) {
        const bool nz = (tagv[tt] != 0);
        cnt += nz ? 1 : 0;
        acc += nz ? vv[tt] : 0.0f;
    }
    float scale = rcpf((float)(cnt > 0 ? cnt : 1));
    float v = (lane < Ee) ? acc * scale : 0.0f;
    gru16[((size_t)t * Bb + b) * 32 + lane] = (_Float16)v;
    if (lane == 0) {
        float m = (tagv[0] != 0) ? 1.0f : 0.0f;
        maskf[group] = m;                       // [b][t] for attn
        maskt[(size_t)t * Bb + b] = m;          // [t][b] for scan
    }
}

// ---------------- Kernel 2: bidirectional LSTM scan via MFMA fp16, MG=4 replicated ----------------
// Grid = 128 blocks (2 dir x 64 batch-groups of 4), 512 threads = 8 waves.
// A rows = 4*batch + replica -> every lane owns all 4 gate-z of ONE cell.
// R10: fragments from wfrag (28 coalesced b128 loads); pointer-increment prefetch.
__global__ void __launch_bounds__(512)
__attribute__((amdgpu_waves_per_eu(2, 2)))
scan_kernel(const _Float16* __restrict__ gru16, const _Float16* __restrict__ skips16,
            const float* __restrict__ maskt,
            const _Float16* __restrict__ wfrag,
            const float* __restrict__ bf, const float* __restrict__ bb,
            _Float16* __restrict__ hs16, float* __restrict__ hfwd)
{
    __shared__ __align__(16) _Float16 h16[2 * MG * HP];

    const int tid = threadIdx.x;
    const int lane = tid & 63;
    const int w = tid >> 6;
    const int l16 = lane & 15;
    const int q = lane >> 4;         // this thread's batch row (0..3)
    const int mb = l16 >> 2;         // A-fragment source batch row (replicated)
    const int bg = blockIdx.x & 63;
    const int dir = blockIdx.x >> 6;
    const int b0 = bg * MG;
    const int col = 16 * w + l16;    // this thread's h column

    const float* bw = dir ? bb : bf;

    // B-fragments from pre-fragmented buffer: 28 coalesced b128 loads
    f16x8 bfr[7][4];
    {
        const _Float16* wfp = wfrag + (size_t)dir * 28 * WFRAG_SZ + col * 32 + q * 8;
#pragma unroll
        for (int kt = 0; kt < 7; kt++)
#pragma unroll
            for (int g = 0; g < 4; g++)
                bfr[kt][g] = *(const f16x8*)(wfp + (kt * 4 + g) * WFRAG_SZ);
    }
    const float gs[4] = {LOG2E, LOG2E, 2.0f * LOG2E, LOG2E};
    float biasv[4];
#pragma unroll
    for (int g = 0; g < 4; g++) biasv[g] = bw[g * Hh + col] * gs[g];

    for (int idx = tid; idx < 2 * MG * HP; idx += 512) h16[idx] = (_Float16)0.0f;

    float c = 0.0f, h = 0.0f;

    // hs16 write pointer; per-step delta +-256 halves
    _Float16* hsp = hs16 + ((size_t)(b0 + q) * Ss + (dir ? Ss - 1 : 0)) * (2 * Hh)
                    + dir * Hh + col;
    const ptrdiff_t odelta = dir ? -(2 * Hh) : (2 * Hh);

    // pointer-increment prefetch streams (pads absorb the depth-2 overrun)
    const int t0 = dir ? (Ss - 1) : 0;
    const _Float16* gp = gru16 + ((size_t)t0 * Bb + b0 + mb) * 32 + 8 * q;
    const ptrdiff_t gdelta = dir ? -(ptrdiff_t)(Bb * 32) : (ptrdiff_t)(Bb * 32);
    const _Float16* sp = skips16 + ((size_t)(b0 + mb) * Ss + t0) * SKIPn + 8 * q;
    const ptrdiff_t sdelta = dir ? -(ptrdiff_t)SKIPn : (ptrdiff_t)SKIPn;
    const float* mp = maskt + (size_t)t0 * Bb + b0 + q;
    const ptrdiff_t mdelta = dir ? -(ptrdiff_t)Bb : (ptrdiff_t)Bb;

    auto issue_xs = [&](f16x8& xf, f16x8& s0, f16x8& s1) {
        xf = *(const f16x8*)(gp);
        s0 = *(const f16x8*)(sp);
        s1 = *(const f16x8*)(sp + 32);
        gp += gdelta; sp += sdelta;
    };
    auto issue_m = [&](float& mk) {
        mk = *mp; mp += mdelta;
    };

    // 2-slot depth-2 prefetch
    f16x8 xA, xB, sA0, sA1, sB0, sB1;
    float mA, mB;
    issue_xs(xA, sA0, sA1); issue_m(mA);
    issue_xs(xB, sB0, sB1); issue_m(mB);
    __syncthreads();

    auto body = [&](int i, f16x8& xf, f16x8& s0, f16x8& s1, float& mkv) {
        // h fragments first: ds latency hides under the x/s MFMAs
        const _Float16* hb = h16 + (i & 1) * (MG * HP);
        const f16x8 ah0 = *(const f16x8*)(hb + mb * HP +  0 + 8 * q);
        const f16x8 ah1 = *(const f16x8*)(hb + mb * HP + 32 + 8 * q);
        const f16x8 ah2 = *(const f16x8*)(hb + mb * HP + 64 + 8 * q);
        const f16x8 ah3 = *(const f16x8*)(hb + mb * HP + 96 + 8 * q);

        f32x4 acc[4];
#pragma unroll
        for (int g = 0; g < 4; g++) {
            f32x4 a = {biasv[g], biasv[g], biasv[g], biasv[g]};
            acc[g] = a;
        }
#pragma unroll
        for (int g = 0; g < 4; g++) {
            acc[g] = __builtin_amdgcn_mfma_f32_16x16x32_f16(xf, bfr[0][g], acc[g], 0, 0, 0);
            acc[g] = __builtin_amdgcn_mfma_f32_16x16x32_f16(s0, bfr[5][g], acc[g], 0, 0, 0);
            acc[g] = __builtin_amdgcn_mfma_f32_16x16x32_f16(s1, bfr[6][g], acc[g], 0, 0, 0);
        }
        // refill x/s for step i+2 AFTER their last use (no fragment copies)
        issue_xs(xf, s0, s1);
#pragma unroll
        for (int g = 0; g < 4; g++) {
            acc[g] = __builtin_amdgcn_mfma_f32_16x16x32_f16(ah0, bfr[1][g], acc[g], 0, 0, 0);
            acc[g] = __builtin_amdgcn_mfma_f32_16x16x32_f16(ah1, bfr[2][g], acc[g], 0, 0, 0);
            acc[g] = __builtin_amdgcn_mfma_f32_16x16x32_f16(ah2, bfr[3][g], acc[g], 0, 0, 0);
            acc[g] = __builtin_amdgcn_mfma_f32_16x16x32_f16(ah3, bfr[4][g], acc[g], 0, 0, 0);
        }

        // ---- gates: 1 cell/thread (batch q, col)
        const float mk = mkv;
        issue_m(mkv);
        const float zi = acc[0][0], zf = acc[1][0], zg = acc[2][0], zo = acc[3][0];
        const float ei = exp2f_(fminf(-zi, 88.0f));   // e^{-z_i}
        const float ef = exp2f_(fminf(-zf, 88.0f));
        const float eg = exp2f_(fminf(-zg, 88.0f));   // e^{-2 z_g}
        const float eo = exp2f_(fminf(-zo, 88.0f));
        const float pi = 1.0f + ei, pg = 1.0f + eg, pf = 1.0f + ef;
        const float p  = pi * pg;
        const float t1 = (1.0f - eg) * pf;
        const float cn = fmaf(c, p, t1) * rcpf(pf * p);
        const float ec = exp2f_(fminf(cn * (-2.0f * LOG2E), 88.0f));   // e^{-2 cn}
        const float hn = (1.0f - ec) * rcpf((1.0f + eo) * (1.0f + ec));
        const bool mm = (mk != 0.0f);
        c = mm ? cn : c;
        h = mm ? hn : h;

        _Float16* hw = h16 + ((i + 1) & 1) * (MG * HP);
        hw[q * HP + col] = (_Float16)h;
        *hsp = (_Float16)h;
        hsp += odelta;
        lgkm_barrier();
    };

#pragma unroll 1
    for (int i = 0; i < Ss; i += 2) {
        body(i,     xA, sA0, sA1, mA);
        body(i + 1, xB, sB0, sB1, mB);
    }

    if (dir == 0) hfwd[(size_t)(b0 + q) * Hh + col] = h;
}

// ---------------- Kernel 3: fused attention: q + energy + softmax + context ----------------
// Grid = 256 blocks (1 per batch), 512 threads = 8 waves.
__global__ void __launch_bounds__(512)
attn_kernel(const _Float16* __restrict__ hs16, const float* __restrict__ hfwd,
            const float* __restrict__ Wq, const float* __restrict__ bq,
            const float* __restrict__ bk,
            const _Float16* __restrict__ wkfrag, const float* __restrict__ We,
            const float* __restrict__ maskf, float* __restrict__ outp)
{
    __shared__ float hfl[Hh];
    __shared__ float qpart[4][Hh];
    __shared__ float qtot_s[Hh];
    __shared__ float epart[8][Ss];      // [wave][s] transposed: conflict-free
    __shared__ float ws2[Ss];           // softmax weights, transposed (s&31)*16+(s>>5)
    __shared__ float redm[8], reds[8];
    __shared__ float ctxp[16][2 * Hh + 1];  // pitch 257: ~2-way max

    const int tid = threadIdx.x;
    const int lane = tid & 63;
    const int w = tid >> 6;
    const int l16 = lane & 15;
    const int q = lane >> 4;
    const int b = blockIdx.x;
    const int j = 16 * w + l16;         // this wave's j-column (0..127)

    // Wk B-fragments from pre-fragmented buffer: 8 coalesced b128 loads
    f16x8 bk16[8];
    {
        const _Float16* wkp = wkfrag + j * 32 + q * 8;
#pragma unroll
        for (int kt = 0; kt < 8; kt++)
            bk16[kt] = *(const f16x8*)(wkp + kt * WFRAG_SZ);
    }
    const float wej = We[j];

    // ---- phase 0: qtot = hfwd[b] @ Wq + bq + bk
    if (tid < Hh) hfl[tid] = hfwd[(size_t)b * Hh + tid];
    __syncthreads();
    {
        const int jj = tid & 127, seg = tid >> 7;
        float p = 0.0f;
#pragma unroll
        for (int k = 0; k < 32; k++)
            p += hfl[32 * seg + k] * Wq[(32 * seg + k) * Hh + jj];
        qpart[seg][jj] = p;
    }
    __syncthreads();
    if (tid < Hh)
        qtot_s[tid] = qpart[0][tid] + qpart[1][tid] + qpart[2][tid] + qpart[3][tid]
                      + bq[tid] + bk[tid];
    __syncthreads();
    const float qj = qtot_s[j];

    // ---- phase 1: energy partials via MFMA (each wave: all 32 s-tiles, its 16 j)
    const _Float16* hb = hs16 + (size_t)b * Ss * (2 * Hh);
#pragma unroll 1
    for (int st = 0; st < 32; st++) {
        const int s0 = st * 16;
        const _Float16* arow = hb + (size_t)(s0 + l16) * (2 * Hh) + 8 * q;
        f32x4 acc = {0.f, 0.f, 0.f, 0.f};
#pragma unroll
        for (int kt = 0; kt < 8; kt++) {
            const f16x8 a = *(const f16x8*)(arow + 32 * kt);
            acc = __builtin_amdgcn_mfma_f32_16x16x32_f16(a, bk16[kt], acc, 0, 0, 0);
        }
        float vals[4];
#pragma unroll
        for (int r = 0; r < 4; r++) {
            const float x = acc[r] + qj;
            const float e = exp2f_(fminf(x * (-2.0f * LOG2E), 80.0f));
            vals[r] = (1.0f - e) * rcpf(1.0f + e) * wej;   // tanh(x)*We[j]
        }
#pragma unroll
        for (int m = 1; m < 16; m <<= 1) {
#pragma unroll
            for (int r = 0; r < 4; r++) vals[r] += __shfl_xor(vals[r], m);
        }
        if (l16 == 0) {
#pragma unroll
            for (int r = 0; r < 4; r++) epart[w][s0 + 4 * q + r] = vals[r];
        }
    }
    __syncthreads();

    // ---- phase 2: masked softmax over S (thread tid owns s=tid)
    {
        float e = 0.0f;
#pragma unroll
        for (int ww = 0; ww < 8; ww++) e += epart[ww][tid];
        e += (1.0f - maskf[(size_t)b * Ss + tid]) * -1e9f;
        float mx = e;
#pragma unroll
        for (int off = 32; off > 0; off >>= 1) mx = fmaxf(mx, __shfl_xor(mx, off));
        if (lane == 0) redm[w] = mx;
        __syncthreads();
        mx = redm[0];
#pragma unroll
        for (int ww = 1; ww < 8; ww++) mx = fmaxf(mx, redm[ww]);
        const float p = exp2f_((e - mx) * LOG2E);
        float sm = p;
#pragma unroll
        for (int off = 32; off > 0; off >>= 1) sm += __shfl_xor(sm, off);
        if (lane == 0) reds[w] = sm;
        __syncthreads();
        sm = reds[0] + reds[1] + reds[2] + reds[3] + reds[4] + reds[5] + reds[6] + reds[7];
        ws2[(tid & 31) * 16 + (tid >> 5)] = p * rcpf(sm);
    }
    __syncthreads();

    // ---- phase 3: context. thread = (colgrp cg = tid>>4: cols 8cg..8cg+7, seg = tid&15)
    {
        const int cg = tid >> 4;
        const int seg = tid & 15;
        float a[8];
#pragma unroll
        for (int jj = 0; jj < 8; jj++) a[jj] = 0.0f;
#pragma unroll 4
        for (int sg = 0; sg < 32; sg++) {
            const int s = seg * 32 + sg;
            const float wv = ws2[sg * 16 + seg];
            const f16x8 hv = *(const f16x8*)(hb + (size_t)s * (2 * Hh) + 8 * cg);
#pragma unroll
            for (int jj = 0; jj < 8; jj++) a[jj] = fmaf(wv, (float)hv[jj], a[jj]);
        }
#pragma unroll
        for (int jj = 0; jj < 8; jj++) ctxp[seg][8 * cg + jj] = a[jj];
    }
    __syncthreads();
    if (tid < 2 * Hh) {
        float s = 0.0f;
#pragma unroll
        for (int seg = 0; seg < 16; seg++) s += ctxp[seg][tid];
        outp[(size_t)b * (2 * Hh) + tid] = s;
    }
}

// ---------------- Launcher ----------------
extern "C" void kernel_launch(void* const* d_in, const int* in_sizes, int n_in,
                              void* d_out, int out_size, void* d_ws, size_t ws_size,
                              hipStream_t stream) {
    const int*   tags  = (const int*)d_in[0];
    const float* skips = (const float*)d_in[1];
    const float* table = (const float*)d_in[2];
    const float* Kf    = (const float*)d_in[3];
    const float* Rf    = (const float*)d_in[4];
    const float* Skf   = (const float*)d_in[5];
    const float* bf    = (const float*)d_in[6];
    const float* Kb    = (const float*)d_in[7];
    const float* Rb    = (const float*)d_in[8];
    const float* Skb   = (const float*)d_in[9];
    const float* bb    = (const float*)d_in[10];
    const float* Wk    = (const float*)d_in[11];
    const float* bk    = (const float*)d_in[12];
    const float* Wq    = (const float*)d_in[13];
    const float* bq    = (const float*)d_in[14];
    const float* We    = (const float*)d_in[15];

    char* ws = (char*)d_ws;
    // padded streams: depth-2 prefetch overruns both ends
    _Float16* gru16a  = (_Float16*)ws; ws += (size_t)(Ss + 4) * Bb * 32 * 2;   // 8.5 MB
    _Float16* gru16   = gru16a + 2 * Bb * 32;
    _Float16* skips16a = (_Float16*)ws; ws += ((size_t)BSn * SKIPn + 2048) * 2; // 16.8 MB
    _Float16* skips16 = skips16a + 1024;
    float* maskta = (float*)ws;  ws += (size_t)(Ss + 8) * Bb * 4;              // 0.53 MB
    float* maskt  = maskta + 4 * Bb;
    float* maskf  = (float*)ws;  ws += (size_t)BSn * 4;                        // 0.5 MB
    _Float16* hs16 = (_Float16*)ws; ws += (size_t)BSn * 2 * Hh * 2;            // 67.1 MB
    float* hfwd   = (float*)ws;  ws += (size_t)Bb * Hh * 4;
    _Float16* wfrag  = (_Float16*)ws; ws += (size_t)2 * 28 * WFRAG_SZ * 2;     // 0.46 MB
    _Float16* wkfrag = (_Float16*)ws; ws += (size_t)8 * WFRAG_SZ * 2;          // 0.07 MB

    frag_kernel<<<64, 128, 0, stream>>>(Kf, Rf, Skf, Kb, Rb, Skb, Wk, wfrag, wkfrag);
    poolcvt_kernel<<<BSn / 8 + BSn * SKIPn / 2048, 256, 0, stream>>>(
        tags, table, skips, gru16, maskf, maskt, skips16);
    scan_kernel<<<128, 512, 0, stream>>>(gru16, skips16, maskt, wfrag, bf, bb,
                                         hs16, hfwd);
    attn_kernel<<<Bb, 512, 0, stream>>>(hs16, hfwd, Wq, bq, bk, wkfrag, We, maskf,
                                        (float*)d_out);
}